// Round 13
// baseline (105.201 us; speedup 1.0000x reference)
//
#include <hip/hip_runtime.h>
#include <math.h>

#define PP 9       // K*K
#define CAPS 32
#define PS 16
#define OH 15
#define HH 32
#define WW 32
#define LN_2PI 1.8378770664093453f

typedef float f32x2 __attribute__((ext_vector_type(2)));
typedef _Float16 f16x2 __attribute__((ext_vector_type(2)));

__device__ __forceinline__ float frcp(float x) {
    float r;
    asm("v_rcp_f32 %0, %1" : "=v"(r) : "v"(x));
    return r;
}
__device__ __forceinline__ f32x2 splat2(float x) {
    f32x2 r; r.x = x; r.y = x; return r;
}
__device__ __forceinline__ f32x2 pkfma(f32x2 a, f32x2 b, f32x2 c) {
    return __builtin_elementwise_fma(a, b, c);  // -> v_pk_fma_f32 (gfx950 packed fp32)
}

// fp16x2 vote tile (accuracy PROVEN R10-R12: absmax 0.0625 vs 0.234 thresh).
// R12 root cause of the persistent spill: THERE IS NO 3-WAVE OCCUPANCY STEP —
// waves/SIMD halve at VGPR {64,128,256}, so (64,3) clamps the budget to 128;
// our thread peaked ~140-240 -> LLVM spilled the whole vb alloca (64MB
// scratch). This round fits the WHOLE thread in <=128: persistent = vb(72) +
// mu2(16) + is22(16) + r(9) + scalars ~= 118; transients capped by (a) a
// sched_barrier after EVERY pixel in phase 1 (one pixel = 32 f32 in flight)
// and (b) E-step batch groups of 3 chains (6 temps, not 18; R7 proved chain
// overlap granularity is perf-neutral). Target: 4 waves/SIMD = 8 sites in
// flight vs the ~4 every 38us kernel has had.
__device__ __forceinline__ f16x2 pk_f16(f32x2 v) {
    f16x2 h;
    h.x = (_Float16)v.x;   // RNE
    h.y = (_Float16)v.y;
    return h;
}
__device__ __forceinline__ f32x2 unpk(f16x2 h) {
    f32x2 r;
    r.x = (float)h.x;
    r.y = (float)h.y;
    return r;
}

// DPP helpers (VALU pipe): quad_perm xor1=0xB1, xor2=0x4E; row_ror:4=0x124, row_ror:8=0x128.
template <int CTRL>
__device__ __forceinline__ float dppf(float x) {
    int r = __builtin_amdgcn_update_dpp(0, __builtin_bit_cast(int, x), CTRL, 0xF, 0xF, true);
    return __builtin_bit_cast(float, r);
}
__device__ __forceinline__ float row_sum16(float x) {
    x += dppf<0xB1>(x);
    x += dppf<0x4E>(x);
    x += dppf<0x124>(x);
    x += dppf<0x128>(x);
    return x;
}
__device__ __forceinline__ float row_max16(float x) {
    x = fmaxf(x, dppf<0xB1>(x));
    x = fmaxf(x, dppf<0x4E>(x));
    x = fmaxf(x, dppf<0x124>(x));
    x = fmaxf(x, dppf<0x128>(x));
    return x;
}
// xor16 within each 32-lane group (and-mask 0x1F) -> halves (= the 2 sites)
// stay independent. PROVEN primitive. permlane16_swap failed twice (R5/R6:
// identical inputs coalesce to one register -> in-place rotation). Keep this.
__device__ __forceinline__ float swz_xor16(float x) {
    return __builtin_bit_cast(float,
        __builtin_amdgcn_ds_swizzle(__builtin_bit_cast(int, x), 0x401F));
}

// Layout: each 64-lane wave = TWO sites (32 lanes each), lane = s*32 + c;
// thread owns all 16 pose elems of capsule c of site s (softmax amortized
// over 2 sites — split-PS and split-K both measured worse). Pose math packed
// f32x2 (v_pk_fma_f32); EM loop rolled (one E+M copy in the binary).
__global__ __launch_bounds__(64, 4) void emcaps_kernel(
    const float* __restrict__ x,      // (32,32,32,32,16)
    const float* __restrict__ a,      // (32,32,32,32)
    const float* __restrict__ wgt,    // (9,32,4,4)
    const float* __restrict__ beta_u, // (32)
    const float* __restrict__ beta_a, // (32)
    float* __restrict__ out_mu,       // (32,15,15,32,16)
    float* __restrict__ out_a)        // (32,15,15,32)
{
    const int lane = threadIdx.x;   // 0..63
    const int s = lane >> 5;        // site within pair
    const int c = lane & 31;        // capsule

    const int site = blockIdx.x * 2 + s;
    const int j = site % OH;
    const int t2 = site / OH;
    const int i = t2 % OH;
    const int b = t2 / OH;
    const int h0 = 2 * i, w0 = 2 * j;

    f16x2 vb[PP][8];   // fp16x2 votes: pair m = pose elems (2m, 2m+1)
    float r[PP];

    // ---- phase 1: per pixel {load x, vote, pack}, FENCED after every pixel
    // so only ONE pixel's xt+wl (32 f32) is ever in flight on top of vb ----
    #pragma unroll
    for (int k = 0; k < PP; ++k) {
        const int hh = h0 + k / 3, ww = w0 + k % 3;
        const size_t pix = (size_t)(b * HH + hh) * WW + ww;
        const float* xb = x + pix * (CAPS * PS) + c * PS;
        float xt[PS];
        *(float4*)&xt[0]  = *(const float4*)xb;
        *(float4*)&xt[4]  = *(const float4*)(xb + 4);
        *(float4*)&xt[8]  = *(const float4*)(xb + 8);
        *(float4*)&xt[12] = *(const float4*)(xb + 12);
        r[k] = a[pix * CAPS + c] * (1.f / 32.f);  // initial r (it0)

        float wl[PS];
        const float* wb = wgt + k * (CAPS * PS) + c * PS;
        *(float4*)&wl[0]  = *(const float4*)wb;
        *(float4*)&wl[4]  = *(const float4*)(wb + 4);
        *(float4*)&wl[8]  = *(const float4*)(wb + 8);
        *(float4*)&wl[12] = *(const float4*)(wb + 12);

        // vote[t] = sum_q xt[(t&12)+q] * wl[q*4+(t&3)]; pair m = (2m, 2m+1)
        #pragma unroll
        for (int m = 0; m < 8; ++m) {
            f32x2 acc = splat2(0.f);
            #pragma unroll
            for (int q = 0; q < 4; ++q) {
                f32x2 w2; w2.x = wl[q * 4 + ((2 * m) & 3)]; w2.y = wl[q * 4 + ((2 * m + 1) & 3)];
                acc = pkfma(splat2(xt[((2 * m) & 12) + q]), w2, acc);
            }
            vb[k][m] = pk_f16(acc);
        }
        // register-pressure fence: pixel k+1's loads may not hoist above here
        __builtin_amdgcn_sched_barrier(0);
    }

    const float bu = beta_u[c];
    const float ba = beta_a[c];
    const float eps = 1e-6f;
    const float lam = 1e-3f;

    f32x2 mu2[8], is22[8];   // is22 = 1/(2*sigma^2)
    float aoc = 0.f;
    float slgfull = 0.f;
    float r_sum;

    #pragma unroll 1   // one copy of E+M in the binary; limits live-range blowup
    for (int it = 0; it < 3; ++it) {
        if (it > 0) {
            // ---- E-step: batched in GROUPS OF 3 chains (6 temp regs, not 18).
            // R7 proved chain-overlap granularity is perf-neutral; what matters
            // here is the 128-reg fit. ----
            const float addc = __logf(aoc) - slgfull - 8.f * LN_2PI;
            #pragma unroll
            for (int g = 0; g < 3; ++g) {
                float lnk[3], red[3];
                #pragma unroll
                for (int kk = 0; kk < 3; ++kk) {      // A: ln-posteriors
                    const int k = 3 * g + kk;
                    f32x2 s2 = splat2(0.f);
                    #pragma unroll
                    for (int m = 0; m < 8; ++m) {
                        f32x2 d = unpk(vb[k][m]) - mu2[m];
                        s2 = pkfma(d * d, is22[m], s2);
                    }
                    lnk[kk] = addc - (s2.x + s2.y);
                }
                #pragma unroll
                for (int kk = 0; kk < 3; ++kk) red[kk] = row_max16(lnk[kk]);   // B
                #pragma unroll
                for (int kk = 0; kk < 3; ++kk)                                 // C
                    red[kk] = fmaxf(red[kk], swz_xor16(red[kk]));
                #pragma unroll
                for (int kk = 0; kk < 3; ++kk) lnk[kk] = __expf(lnk[kk] - red[kk]); // D
                #pragma unroll
                for (int kk = 0; kk < 3; ++kk) red[kk] = row_sum16(lnk[kk]);   // E
                #pragma unroll
                for (int kk = 0; kk < 3; ++kk)                                 // F
                    red[kk] += swz_xor16(red[kk]);
                #pragma unroll
                for (int kk = 0; kk < 3; ++kk)                                 // G
                    r[3 * g + kk] = lnk[kk] * frcp(red[kk]);
                __builtin_amdgcn_sched_barrier(0);   // keep groups from merging
            }
        }

        // ---- M-step: two-pass (numerically required; expanded quadratic
        //      forms rejected — catastrophic cancellation class) ----
        r_sum = 0.f;
        #pragma unroll
        for (int k = 0; k < PP; ++k) r_sum += r[k];
        const float invr = frcp(r_sum + eps);
        #pragma unroll
        for (int k = 0; k < PP; ++k) r[k] *= invr;   // coeff

        #pragma unroll
        for (int m = 0; m < 8; ++m) {
            f32x2 acc = splat2(0.f);
            #pragma unroll
            for (int k = 0; k < PP; ++k) acc = pkfma(splat2(r[k]), unpk(vb[k][m]), acc);
            mu2[m] = acc;
        }
        float slg = 0.f;
        #pragma unroll
        for (int m = 0; m < 8; ++m) {
            f32x2 acc = splat2(0.f);
            #pragma unroll
            for (int k = 0; k < PP; ++k) {
                f32x2 d = unpk(vb[k][m]) - mu2[m];
                acc = pkfma(splat2(r[k]) * d, d, acc);
            }
            f32x2 sg = acc + splat2(eps);
            is22[m].x = frcp(2.f * sg.x);
            is22[m].y = frcp(2.f * sg.y);
            slg += 0.5f * __logf(sg.x * sg.y);   // = 0.5*(log sx + log sy)
        }
        slgfull = slg;
        const float ch = r_sum * (16.f * bu + slgfull);
        aoc = frcp(1.f + __expf(-lam * (ba - ch)));
    }

    // ---- outputs: each thread stores its 16 mu's (64B) + its a ----
    float* ob = out_mu + (size_t)site * (CAPS * PS) + c * PS;
    *(float4*)(ob + 0)  = *(float4*)&mu2[0];
    *(float4*)(ob + 4)  = *(float4*)&mu2[2];
    *(float4*)(ob + 8)  = *(float4*)&mu2[4];
    *(float4*)(ob + 12) = *(float4*)&mu2[6];
    out_a[(size_t)site * CAPS + c] = aoc;
}

extern "C" void kernel_launch(void* const* d_in, const int* in_sizes, int n_in,
                              void* d_out, int out_size, void* d_ws, size_t ws_size,
                              hipStream_t stream) {
    const float* x      = (const float*)d_in[0];
    const float* a      = (const float*)d_in[1];
    const float* wgt    = (const float*)d_in[2];
    const float* beta_u = (const float*)d_in[3];
    const float* beta_a = (const float*)d_in[4];

    float* out_mu = (float*)d_out;
    float* out_a  = (float*)d_out + (size_t)32 * OH * OH * CAPS * PS;  // 3,686,400

    const int n_sites = 32 * OH * OH;  // 7200
    emcaps_kernel<<<n_sites / 2, 64, 0, stream>>>(x, a, wgt, beta_u, beta_a, out_mu, out_a);
}

// Round 14
// 37.981 us; speedup vs baseline: 2.7699x; 2.7699x over previous
//
#include <hip/hip_runtime.h>
#include <math.h>

#define PP 9       // K*K
#define CAPS 32
#define PS 16
#define OH 15
#define HH 32
#define WW 32
#define LN_2PI 1.8378770664093453f

typedef float f32x2 __attribute__((ext_vector_type(2)));

__device__ __forceinline__ float frcp(float x) {
    float r;
    asm("v_rcp_f32 %0, %1" : "=v"(r) : "v"(x));
    return r;
}
__device__ __forceinline__ f32x2 splat2(float x) {
    f32x2 r; r.x = x; r.y = x; return r;
}
__device__ __forceinline__ f32x2 pkfma(f32x2 a, f32x2 b, f32x2 c) {
    return __builtin_elementwise_fma(a, b, c);  // -> v_pk_fma_f32 (gfx950 packed fp32)
}

// DPP helpers (VALU pipe): quad_perm xor1=0xB1, xor2=0x4E; row_ror:4=0x124, row_ror:8=0x128.
template <int CTRL>
__device__ __forceinline__ float dppf(float x) {
    int r = __builtin_amdgcn_update_dpp(0, __builtin_bit_cast(int, x), CTRL, 0xF, 0xF, true);
    return __builtin_bit_cast(float, r);
}
__device__ __forceinline__ float row_sum16(float x) {
    x += dppf<0xB1>(x);
    x += dppf<0x4E>(x);
    x += dppf<0x124>(x);
    x += dppf<0x128>(x);
    return x;
}
__device__ __forceinline__ float row_max16(float x) {
    x = fmaxf(x, dppf<0xB1>(x));
    x = fmaxf(x, dppf<0x4E>(x));
    x = fmaxf(x, dppf<0x124>(x));
    x = fmaxf(x, dppf<0x128>(x));
    return x;
}
// xor16 within each 32-lane group (and-mask 0x1F) -> halves (= the 2 sites)
// stay independent. PROVEN primitive (R3, 38.2us). permlane16_swap was tried
// twice (R5 asm, R6 builtin) and both times the allocator coalesced the two
// identical inputs into ONE register -> in-place row rotation -> 2*x[lane^16]
// instead of x + x[lane^16]. Do not retry with identical inputs.
__device__ __forceinline__ float swz_xor16(float x) {
    return __builtin_bit_cast(float,
        __builtin_amdgcn_ds_swizzle(__builtin_bit_cast(int, x), 0x401F));
}

// FINAL KERNEL (R7 = best verified: 38.13us, absmax 0.03125).
// Layout: one 64-lane wave = TWO sites (32 lanes each), lane = s*32 + c;
// each thread owns all 16 pose elems of capsule c of site s. All pose math
// packed f32x2 (v_pk_fma_f32); E-step phase-batched; softmax via DPP +
// ds_swizzle within each 32-lane half, amortized over 2 sites/wave.
//
// Why this is the floor (R0-R13 evidence):
//  - wall invariant to HBM traffic (R2: FETCH -50% -> nil), issue count
//    (R3: busy -21% -> wall -4%), cross-lane latency (R7: nil), I$ (R8: nil);
//  - latency-bound at 4 sites-in-flight/SIMD: vote state (18.4KB f32/site)
//    puts 16 sites/CU at 295KB of the 512KB regfile; doubling needs 590KB
//    f32 (impossible) or a <=128-reg fp16 thread (allocator spills the tile
//    wholesale: R10-R13, 64-146MB scratch, 72-105us); LDS (160KB/CU) holds
//    fewer sites than the regfile -> strictly dominated.
__global__ __launch_bounds__(64, 2) void emcaps_kernel(
    const float* __restrict__ x,      // (32,32,32,32,16)
    const float* __restrict__ a,      // (32,32,32,32)
    const float* __restrict__ wgt,    // (9,32,4,4)
    const float* __restrict__ beta_u, // (32)
    const float* __restrict__ beta_a, // (32)
    float* __restrict__ out_mu,       // (32,15,15,32,16)
    float* __restrict__ out_a)        // (32,15,15,32)
{
    const int lane = threadIdx.x;   // 0..63
    const int s = lane >> 5;        // site within pair
    const int c = lane & 31;        // capsule

    const int site = blockIdx.x * 2 + s;
    const int j = site % OH;
    const int t2 = site / OH;
    const int i = t2 % OH;
    const int b = t2 / OH;
    const int h0 = 2 * i, w0 = 2 * j;

    // ---- phase 1: all global loads issued back-to-back ----
    f32x2 v[PP][8];    // holds x now; overwritten with votes in phase 2
    float r[PP];
    #pragma unroll
    for (int k = 0; k < PP; ++k) {
        const int hh = h0 + k / 3, ww = w0 + k % 3;
        const size_t pix = (size_t)(b * HH + hh) * WW + ww;
        const float* xb = x + pix * (CAPS * PS) + c * PS;
        *(float4*)&v[k][0] = *(const float4*)xb;
        *(float4*)&v[k][2] = *(const float4*)(xb + 4);
        *(float4*)&v[k][4] = *(const float4*)(xb + 8);
        *(float4*)&v[k][6] = *(const float4*)(xb + 12);
        r[k] = a[pix * CAPS + c] * (1.f / 32.f);  // initial r (it0)
    }

    // ---- phase 2: votes in place (weights are L1-hot: 18 KB total) ----
    // pair m covers t=(2m,2m+1): x row idx 4*(m>>1)+q; weight pair w2[q*2+(m&1)].
    #pragma unroll
    for (int k = 0; k < PP; ++k) {
        float xt[PS];
        #pragma unroll
        for (int m = 0; m < 8; ++m) { xt[2 * m] = v[k][m].x; xt[2 * m + 1] = v[k][m].y; }
        f32x2 w2[8];
        const float* wb = wgt + k * (CAPS * PS) + c * PS;
        *(float4*)&w2[0] = *(const float4*)wb;
        *(float4*)&w2[2] = *(const float4*)(wb + 4);
        *(float4*)&w2[4] = *(const float4*)(wb + 8);
        *(float4*)&w2[6] = *(const float4*)(wb + 12);
        #pragma unroll
        for (int m = 0; m < 8; ++m) {
            f32x2 acc = splat2(0.f);
            #pragma unroll
            for (int q = 0; q < 4; ++q)
                acc = pkfma(splat2(xt[4 * (m >> 1) + q]), w2[q * 2 + (m & 1)], acc);
            v[k][m] = acc;
        }
    }

    const float bu = beta_u[c];
    const float ba = beta_a[c];
    const float eps = 1e-6f;
    const float lam = 1e-3f;

    f32x2 mu2[8], is22[8];   // is22 = 1/(2*sigma^2)
    float aoc = 0.f;
    float slgfull = 0.f;
    float r_sum;

    for (int it = 0; it < 3; ++it) {
        if (it > 0) {
            // ---- E-step: phase-batched across the 9 independent k-chains ----
            const float addc = __logf(aoc) - slgfull - 8.f * LN_2PI;
            float lnk[PP], red[PP];
            #pragma unroll
            for (int k = 0; k < PP; ++k) {          // phase A: ln-posteriors
                f32x2 s2 = splat2(0.f);
                #pragma unroll
                for (int m = 0; m < 8; ++m) {
                    f32x2 d = v[k][m] - mu2[m];
                    s2 = pkfma(d * d, is22[m], s2);
                }
                lnk[k] = addc - (s2.x + s2.y);
            }
            #pragma unroll
            for (int k = 0; k < PP; ++k) red[k] = row_max16(lnk[k]);   // B: DPP maxes
            #pragma unroll
            for (int k = 0; k < PP; ++k)                                // C: 9 swizzles
                red[k] = fmaxf(red[k], swz_xor16(red[k]));              //    pipelined
            #pragma unroll
            for (int k = 0; k < PP; ++k) lnk[k] = __expf(lnk[k] - red[k]); // D: exps
            #pragma unroll
            for (int k = 0; k < PP; ++k) red[k] = row_sum16(lnk[k]);   // E: DPP sums
            #pragma unroll
            for (int k = 0; k < PP; ++k)                                // F: 9 swizzles
                red[k] += swz_xor16(red[k]);                            //    pipelined
            #pragma unroll
            for (int k = 0; k < PP; ++k) r[k] = lnk[k] * frcp(red[k]); // G: normalize
        }

        // ---- M-step: two-pass (numerically required) ----
        r_sum = 0.f;
        #pragma unroll
        for (int k = 0; k < PP; ++k) r_sum += r[k];
        const float invr = frcp(r_sum + eps);
        f32x2 rr[PP];
        #pragma unroll
        for (int k = 0; k < PP; ++k) { r[k] *= invr; rr[k] = splat2(r[k]); }

        #pragma unroll
        for (int m = 0; m < 8; ++m) {
            f32x2 acc = splat2(0.f);
            #pragma unroll
            for (int k = 0; k < PP; ++k) acc = pkfma(rr[k], v[k][m], acc);
            mu2[m] = acc;
        }
        float slg = 0.f;
        #pragma unroll
        for (int m = 0; m < 8; ++m) {
            f32x2 acc = splat2(0.f);
            #pragma unroll
            for (int k = 0; k < PP; ++k) {
                f32x2 d = v[k][m] - mu2[m];
                acc = pkfma(rr[k] * d, d, acc);
            }
            f32x2 sg = acc + splat2(eps);
            is22[m].x = frcp(2.f * sg.x);
            is22[m].y = frcp(2.f * sg.y);
            slg += 0.5f * __logf(sg.x * sg.y);   // = 0.5*(log sx + log sy)
        }
        slgfull = slg;
        const float ch = r_sum * (16.f * bu + slgfull);
        aoc = frcp(1.f + __expf(-lam * (ba - ch)));
    }

    // ---- outputs: each thread stores its 16 mu's (64B) + its a ----
    float* ob = out_mu + (size_t)site * (CAPS * PS) + c * PS;
    *(float4*)(ob + 0)  = *(float4*)&mu2[0];
    *(float4*)(ob + 4)  = *(float4*)&mu2[2];
    *(float4*)(ob + 8)  = *(float4*)&mu2[4];
    *(float4*)(ob + 12) = *(float4*)&mu2[6];
    out_a[(size_t)site * CAPS + c] = aoc;
}

extern "C" void kernel_launch(void* const* d_in, const int* in_sizes, int n_in,
                              void* d_out, int out_size, void* d_ws, size_t ws_size,
                              hipStream_t stream) {
    const float* x      = (const float*)d_in[0];
    const float* a      = (const float*)d_in[1];
    const float* wgt    = (const float*)d_in[2];
    const float* beta_u = (const float*)d_in[3];
    const float* beta_a = (const float*)d_in[4];

    float* out_mu = (float*)d_out;
    float* out_a  = (float*)d_out + (size_t)32 * OH * OH * CAPS * PS;  // 3,686,400

    const int n_sites = 32 * OH * OH;  // 7200
    emcaps_kernel<<<n_sites / 2, 64, 0, stream>>>(x, a, wgt, beta_u, beta_a, out_mu, out_a);
}